// Round 11
// baseline (501.794 us; speedup 1.0000x reference)
//
#include <hip/hip_runtime.h>

typedef unsigned short u16;
typedef unsigned int u32;
typedef unsigned char u8;
typedef int v8i __attribute__((ext_vector_type(8)));
typedef int v4i __attribute__((ext_vector_type(4)));
typedef float v16f __attribute__((ext_vector_type(16)));

#define INV_SQRT32 0.17677669529663688f

// ---------------------------------------------------------------------------
// Stage 1: per-32-group FWHT + MXFP4 quantize (UNCHANGED from round 10).
// Output layout (tile = 128 rows x 128 k):
//   data chunk16 (row, kb): tile*8192 + (kb&3)*2048 + (row&127)*16
//   scale u32   (row):      tile*512 + (row&31)*16 + ((row>>5)&3)*4
// ---------------------------------------------------------------------------
#define QOFS_OUT 32768
#define QOFS_SC  36864

__global__ __launch_bounds__(256) void rotquant4_kernel(
    const float* __restrict__ T, u8* __restrict__ Q4, u8* __restrict__ S,
    int K, int ntk, int nkb /* K/1024 */)
{
    __shared__ __align__(16) u8 smem[37120];

    const int tid  = threadIdx.x;
    const int bid  = blockIdx.x;
    const int rblk = bid / nkb;
    const int kblk = bid - rblk * nkb;
    const int row0 = rblk * 8;
    const int kb0  = kblk * 32;
    const int t0g  = (row0 >> 7) * ntk + (kb0 >> 2);
    const int rl   = row0 & 127;

    {
        const float4* src = (const float4*)T;
#pragma unroll
        for (int j = 0; j < 8; ++j) {
            float4 t = src[(size_t)(row0 + j) * (K >> 2) + (kblk << 8) + tid];
            int kb = tid >> 3, i = tid & 7;
            *(float4*)(smem + j * 4096 + kb * 128 + ((i ^ (kb & 7)) << 4)) = t;
        }
    }
    __syncthreads();

    {
        const int rr = tid >> 5;
        const int kb = tid & 31;

        float v[32];
#pragma unroll
        for (int i = 0; i < 8; ++i) {
            float4 t = *(const float4*)(smem + rr * 4096 + kb * 128
                                        + ((i ^ (kb & 7)) << 4));
            v[i*4+0] = t.x; v[i*4+1] = t.y; v[i*4+2] = t.z; v[i*4+3] = t.w;
        }

#pragma unroll
        for (int s = 1; s < 32; s <<= 1) {
#pragma unroll
            for (int i = 0; i < 32; ++i) {
                if (!(i & s)) {
                    float a = v[i], b = v[i | s];
                    v[i] = a + b;
                    v[i | s] = a - b;
                }
            }
        }

        float amax = 0.f;
#pragma unroll
        for (int i = 0; i < 32; ++i) {
            v[i] *= INV_SQRT32;
            amax = fmaxf(amax, fabsf(v[i]));
        }

        u32 ab = __float_as_uint(amax);
        int be = (int)(ab >> 23);
        u32 w[4] = {0u, 0u, 0u, 0u};
        u8 sbyte = 0;
        if (be >= 3) {
            sbyte = (u8)(be - 2);               // E8M0 of 2^(be-129)
            float iscale = __uint_as_float((u32)(256 - be) << 23);
#pragma unroll
            for (int i = 0; i < 32; ++i) {
                float a = v[i] * iscale;        // exact
                float m = fminf(fabsf(a), 6.0f);
                int c = (m < 0.25f) ? 0 :
                        (m < 0.75f) ? 1 :
                        (m < 1.25f) ? 2 :
                        (m < 1.75f) ? 3 :
                        (m < 2.5f)  ? 4 :
                        (m < 3.5f)  ? 5 :
                        (m < 5.0f)  ? 6 : 7;
                c |= (int)((__float_as_uint(a) >> 28) & 8u);
                w[i >> 3] |= (u32)c << (4 * (i & 7));
            }
        }

        uint4 p; p.x = w[0]; p.y = w[1]; p.z = w[2]; p.w = w[3];
        *(uint4*)(smem + QOFS_OUT + rr * 512 + (kb >> 2) * 64 + (kb & 3) * 16) = p;
        smem[QOFS_SC + rr * 32 + (kb >> 2) * 4 + (kb & 3)] = sbyte;
    }
    __syncthreads();

    {
        int tileL = tid >> 5, slot = (tid >> 3) & 3, rr = tid & 7;
        uint4 p = *(const uint4*)(smem + QOFS_OUT + rr * 512 + tileL * 64
                                  + slot * 16);
        ((uint4*)Q4)[(size_t)(t0g + tileL) * 512 + slot * 128 + rl + rr] = p;
    }
    if (tid < 64) {
        int tileL = tid >> 3, rr = tid & 7;
        u32 sc = *(const u32*)(smem + QOFS_SC + rr * 32 + tileL * 4);
        int r7 = rl + rr;   // row within 128-row tile
        ((u32*)S)[(size_t)(t0g + tileL) * 128 + ((r7 & 31) << 2)
                  + ((r7 >> 5) & 3)] = sc;
    }
}

// ---------------------------------------------------------------------------
// Stage 2: C = deq(A) * deq(B)^T + bias via MX-scaled FP4 MFMA.
// BM=256, BN=256, BK=128, 8 waves (2Mx4N), per-wave 128x64 (4x2 reg-block).
// A (+A scales): LDS-staged, triple-buffered (52 KB), duo pipeline (r10).
// B (+B scales): DIRECT global->VGPR, 1 tile ahead (coalesced dwordx4 from
// the pre-tiled L2-resident workspace) -- removes B's LDS round-trip
// (-32KB read, -16KB write per tile-step on the LDS port).
// Counted vmcnt: per tile issue {6 B loads, 3 A stages}; mid-tile vmcnt(9)
// confirms A(t+1)+B(t) landed; barrier for cross-wave A visibility.
// Unroll 6 (buffers period 3 x B-reg sets period 2); NT=32: 5x6 + 2 epilogue.
// ---------------------------------------------------------------------------
__device__ __forceinline__ void gload16(const void* g, void* l)
{
    __builtin_amdgcn_global_load_lds(
        (__attribute__((address_space(1))) void*)g,
        (__attribute__((address_space(3))) void*)l, 16, 0, 0);
}
__device__ __forceinline__ void gload4(const void* g, void* l)
{
    __builtin_amdgcn_global_load_lds(
        (__attribute__((address_space(1))) void*)g,
        (__attribute__((address_space(3))) void*)l, 4, 0, 0);
}

#define BUF_BYTES 17408   // A data 16 KB @0, A scales 1 KB @16384
#define OFS_AS    16384
#define BB0 0
#define BB1 BUF_BYTES
#define BB2 (2 * BUF_BYTES)

__global__ __launch_bounds__(512, 2) void gemm4_bias(
    const u8* __restrict__ A4, const u8* __restrict__ AS,
    const u8* __restrict__ B4, const u8* __restrict__ BS,
    const float* __restrict__ bias, float* __restrict__ C,
    int M, int N, int K)
{
    __shared__ __align__(16) u8 smem[3 * BUF_BYTES];   // 52224 B

    const int tid  = threadIdx.x;
    const int wave = tid >> 6;
    const int lane = tid & 63;
    const int l31  = lane & 31;
    const int lhi  = lane >> 5;
    const int wm   = wave >> 2;   // 2 (M) x 4 (N) wave grid
    const int wn   = wave & 3;
    const int ntk  = K >> 7;
    const int NT   = ntk;         // 32 for K=4096 (NT % 6 == 2 assumed)

    // XCD-chunked + L2-grouped block ordering
    const int nbn = N >> 8;
    const int nbm = M >> 8;
    int bid = blockIdx.x;
    int bm, bn;
    if (((gridDim.x & 7) == 0) && ((nbm & 7) == 0)) {
        int bpc = nbm >> 3;
        int lb  = __builtin_ctz(bpc);
        int c   = bid & 7;
        int r   = bid >> 3;
        bm = c * bpc + (r & (bpc - 1));
        bn = r >> lb;
    } else {
        bn = bid % nbn;
        bm = bid / nbn;
    }

    v16f acc[4][2];
#pragma unroll
    for (int i = 0; i < 4; ++i)
#pragma unroll
        for (int j = 0; j < 2; ++j)
#pragma unroll
            for (int r = 0; r < 16; ++r) acc[i][j][r] = 0.f;

    // ---- A staging constants (LDS path)
    const size_t aRow0 = (size_t)(2 * bm) * ntk;
    const int w4   = wave & 3;
    const size_t ascT = (size_t)(2 * bm + (w4 >> 1)) * ntk;
    const int ascOfs  = (w4 & 1) * 256 + lane * 4;
    const int gOfs = wave * 1024 + lane * 16;
    const int lOfs = wave * 1024;

    // ---- B direct-load constants (register path)
    const size_t bTileRow = (size_t)(2 * bn + (wn >> 1)) * ntk;
    const int bInner   = lhi * 2048 + ((wn & 1) * 64 + l31) * 16;
    const int bScInner = l31 * 4 + (wn & 1) * 2;     // u32 index

    // ---- per-lane LDS read bases
    const int aRB = wm * 8192 + lhi * 2048 + l31 * 16;   // +mi*512 +ks*4096
    const int asB = OFS_AS + wm * 512 + l31 * 16;        // v4i: u32[mi]
    const int sh0 = lhi * 8;
    const int sh1 = sh0 + 16;

#define STG_A(bofs, kt, r)                                                    \
    gload16(A4 + ((aRow0 + (size_t)(r) * ntk + (kt)) << 13) + gOfs,           \
            smem + (bofs) + (r) * 8192 + lOfs)
#define STG_AS(bofs, kt)                                                      \
    gload4(AS + ((ascT + (kt)) << 9) + ascOfs,                                \
           smem + (bofs) + OFS_AS + w4 * 256)
#define STAGE(bofs, kt)                                                       \
    do { STG_A(bofs, kt, 0); STG_A(bofs, kt, 1); STG_AS(bofs, kt); } while (0)

#define LOADB(B0, B1, B2, B3, SB0, SB1, kt)                                   \
    do {                                                                      \
        const u8* bb_ = B4 + ((bTileRow + (size_t)(kt)) << 13) + bInner;      \
        B0 = *(const v4i*)(bb_);                                              \
        B1 = *(const v4i*)(bb_ + 512);                                        \
        B2 = *(const v4i*)(bb_ + 4096);                                       \
        B3 = *(const v4i*)(bb_ + 4608);                                       \
        const u32* bs_ = (const u32*)(BS + ((bTileRow + (size_t)(kt)) << 9))  \
                         + bScInner;                                          \
        SB0 = bs_[0]; SB1 = bs_[1];                                           \
    } while (0)

#define MK8(x) __builtin_shufflevector(x, x, 0, 1, 2, 3, -1, -1, -1, -1)
#define MFMA1(mi, ni, AF, BF, SA, SB)                                         \
    acc[mi][ni] = __builtin_amdgcn_mfma_scale_f32_32x32x64_f8f6f4(            \
        MK8(AF), MK8(BF), acc[mi][ni], 4, 4, 0, (int)(SA), 0, (int)(SB))

// Pre-set carried across tiles: SAv (A scales), A0a, A0b (ks0 frags mi 0,1)
#define TILE(CO, NO, PO, kt, BC0, BC1, BC2, BC3, SBC0, SBC1,                  \
             BN0_, BN1_, BN2_, BN3_, SBN0_, SBN1_, LDB, ST, REFILL, FINAL, VMN)\
    do {                                                                      \
        if (LDB) LOADB(BN0_, BN1_, BN2_, BN3_, SBN0_, SBN1_, (kt) + 1);       \
        if (ST) STAGE(PO, (kt) + 2);                                          \
        u32 ya0 = ((u32)SAv[0] >> sh0) & 0xffu;                               \
        u32 ya1 = ((u32)SAv[1] >> sh0) & 0xffu;                               \
        u32 ya2 = ((u32)SAv[2] >> sh0) & 0xffu;                               \
        u32 ya3 = ((u32)SAv[3] >> sh0) & 0xffu;                               \
        u32 xa0 = ((u32)SAv[0] >> sh1) & 0xffu;                               \
        u32 xa1 = ((u32)SAv[1] >> sh1) & 0xffu;                               \
        u32 xa2 = ((u32)SAv[2] >> sh1) & 0xffu;                               \
        u32 xa3 = ((u32)SAv[3] >> sh1) & 0xffu;                               \
        u32 yb0 = (SBC0 >> sh0) & 0xffu, yb1 = (SBC1 >> sh0) & 0xffu;         \
        u32 xb0 = (SBC0 >> sh1) & 0xffu, xb1 = (SBC1 >> sh1) & 0xffu;         \
        __builtin_amdgcn_s_setprio(1);                                        \
        v4i a2 = *(const v4i*)(smem + (CO) + aRB + 1024);                     \
        v4i a3 = *(const v4i*)(smem + (CO) + aRB + 1536);                     \
        MFMA1(0, 0, A0a, BC0, ya0, yb0); MFMA1(0, 1, A0a, BC1, ya0, yb1);     \
        v4i a10 = *(const v4i*)(smem + (CO) + aRB + 4096);                    \
        v4i a11 = *(const v4i*)(smem + (CO) + aRB + 4608);                    \
        MFMA1(1, 0, A0b, BC0, ya1, yb0); MFMA1(1, 1, A0b, BC1, ya1, yb1);     \
        v4i a12 = *(const v4i*)(smem + (CO) + aRB + 5120);                    \
        v4i a13 = *(const v4i*)(smem + (CO) + aRB + 5632);                    \
        MFMA1(2, 0, a2, BC0, ya2, yb0); MFMA1(2, 1, a2, BC1, ya2, yb1);       \
        MFMA1(3, 0, a3, BC0, ya3, yb0); MFMA1(3, 1, a3, BC1, ya3, yb1);       \
        __builtin_amdgcn_s_setprio(0);                                        \
        if (!(FINAL)) {                                                       \
            asm volatile("s_waitcnt vmcnt(%0)" :: "i"(VMN) : "memory");       \
            __builtin_amdgcn_s_barrier();                                     \
        }                                                                     \
        __builtin_amdgcn_s_setprio(1);                                        \
        if (REFILL) { SAv = *(const v4i*)(smem + (NO) + asB);                 \
                      A0a = *(const v4i*)(smem + (NO) + aRB);                 \
                      A0b = *(const v4i*)(smem + (NO) + aRB + 512); }         \
        MFMA1(0, 0, a10, BC2, xa0, xb0); MFMA1(0, 1, a10, BC3, xa0, xb1);     \
        MFMA1(1, 0, a11, BC2, xa1, xb0); MFMA1(1, 1, a11, BC3, xa1, xb1);     \
        MFMA1(2, 0, a12, BC2, xa2, xb0); MFMA1(2, 1, a12, BC3, xa2, xb1);     \
        MFMA1(3, 0, a13, BC2, xa3, xb0); MFMA1(3, 1, a13, BC3, xa3, xb1);     \
        __builtin_amdgcn_s_setprio(0);                                        \
    } while (0)

    // ---- B register sets P and Q
    v4i bP0, bP1, bP2, bP3, bQ0, bQ1, bQ2, bQ3;
    u32 sbP0, sbP1, sbQ0, sbQ1;

    // ---- prologue: B(0) -> set P; stage A tiles 0,1; land B(0)+A(0)
    LOADB(bP0, bP1, bP2, bP3, sbP0, sbP1, 0);
    STAGE(BB0, 0);
    STAGE(BB1, 1);
    asm volatile("s_waitcnt vmcnt(3)" ::: "memory");   // B(0)+A(0) landed
    __builtin_amdgcn_s_barrier();

    v4i SAv = *(const v4i*)(smem + BB0 + asB);
    v4i A0a = *(const v4i*)(smem + BB0 + aRB);
    v4i A0b = *(const v4i*)(smem + BB0 + aRB + 512);

    // main: tiles 0..NT-3 in rounds of 6 (NT=32 -> 5 rounds, tiles 0..29)
#pragma unroll 1
    for (int t = 0; t + 7 < NT; t += 6) {
        TILE(BB0, BB1, BB2, t + 0, bP0, bP1, bP2, bP3, sbP0, sbP1,
             bQ0, bQ1, bQ2, bQ3, sbQ0, sbQ1, true, true, true, false, 9);
        TILE(BB1, BB2, BB0, t + 1, bQ0, bQ1, bQ2, bQ3, sbQ0, sbQ1,
             bP0, bP1, bP2, bP3, sbP0, sbP1, true, true, true, false, 9);
        TILE(BB2, BB0, BB1, t + 2, bP0, bP1, bP2, bP3, sbP0, sbP1,
             bQ0, bQ1, bQ2, bQ3, sbQ0, sbQ1, true, true, true, false, 9);
        TILE(BB0, BB1, BB2, t + 3, bQ0, bQ1, bQ2, bQ3, sbQ0, sbQ1,
             bP0, bP1, bP2, bP3, sbP0, sbP1, true, true, true, false, 9);
        TILE(BB1, BB2, BB0, t + 4, bP0, bP1, bP2, bP3, sbP0, sbP1,
             bQ0, bQ1, bQ2, bQ3, sbQ0, sbQ1, true, true, true, false, 9);
        TILE(BB2, BB0, BB1, t + 5, bQ0, bQ1, bQ2, bQ3, sbQ0, sbQ1,
             bP0, bP1, bP2, bP3, sbP0, sbP1, true, true, true, false, 9);
    }
    // epilogue: tile NT-2 (=30, buf0, set P, loads Q, vmcnt(6)); tile NT-1 final
    TILE(BB0, BB1, BB2, NT - 2, bP0, bP1, bP2, bP3, sbP0, sbP1,
         bQ0, bQ1, bQ2, bQ3, sbQ0, sbQ1, true, false, true, false, 6);
    TILE(BB1, BB2, BB0, NT - 1, bQ0, bQ1, bQ2, bQ3, sbQ0, sbQ1,
         bP0, bP1, bP2, bP3, sbP0, sbP1, false, false, false, true, 0);

    // Epilogue: 32x32 C/D: col = lane&31, row = (reg&3)+8*(reg>>2)+4*(lane>>5)
    const int cb = bn * 256 + wn * 64;
    const int rb = bm * 256 + wm * 128;
#pragma unroll
    for (int ni = 0; ni < 2; ++ni) {
        float bb = bias[cb + ni * 32 + l31];
#pragma unroll
        for (int mi = 0; mi < 4; ++mi) {
#pragma unroll
            for (int reg = 0; reg < 16; ++reg) {
                int row = (reg & 3) + 8 * (reg >> 2) + 4 * lhi;
                C[(size_t)(rb + mi * 32 + row) * N + cb + ni * 32 + l31]
                    = acc[mi][ni][reg] + bb;
            }
        }
    }
#undef STG_A
#undef STG_AS
#undef STAGE
#undef LOADB
#undef MK8
#undef MFMA1
#undef TILE
}

// ---------------------------------------------------------------------------
extern "C" void kernel_launch(void* const* d_in, const int* in_sizes, int n_in,
                              void* d_out, int out_size, void* d_ws, size_t ws_size,
                              hipStream_t stream)
{
    const float* x    = (const float*)d_in[0];   // [M, K] = [8192, 4096]
    const float* w    = (const float*)d_in[1];   // [O, K] = [16384, 4096]
    const float* bias = (const float*)d_in[2];   // [O]

    const int O = in_sizes[2];            // 16384
    const int K = in_sizes[1] / O;        // 4096
    const int M = in_sizes[0] / K;        // 8192

    u8* x4 = (u8*)d_ws;                           // [M, K/2]  tiled
    u8* w4 = x4 + (size_t)M * (K / 2);            // [O, K/2]  tiled
    u8* xs = w4 + (size_t)O * (K / 2);            // [M, K/32] tiled
    u8* ws = xs + (size_t)M * (K / 32);           // [O, K/32] tiled

    const int ntk = K / 128;
    const int nkb = K / 1024;
    rotquant4_kernel<<<(M / 8) * nkb, 256, 0, stream>>>(x, x4, xs, K, ntk, nkb);
    rotquant4_kernel<<<(O / 8) * nkb, 256, 0, stream>>>(w, w4, ws, K, ntk, nkb);

    dim3 grid((M / 256) * (O / 256));     // 2048 blocks
    gemm4_bias<<<grid, 512, 0, stream>>>(x4, xs, w4, ws, bias, (float*)d_out,
                                         M, O, K);
}

// Round 12
// 398.047 us; speedup vs baseline: 1.2606x; 1.2606x over previous
//
#include <hip/hip_runtime.h>

typedef unsigned short u16;
typedef unsigned int u32;
typedef unsigned char u8;
typedef int v8i __attribute__((ext_vector_type(8)));
typedef int v4i __attribute__((ext_vector_type(4)));
typedef int v2i __attribute__((ext_vector_type(2)));
typedef float v16f __attribute__((ext_vector_type(16)));

#define INV_SQRT32 0.17677669529663688f

// ---------------------------------------------------------------------------
// Stage 1: per-32-group FWHT + MXFP4 quantize (UNCHANGED from round 10).
// Output layout (tile = 128 rows x 128 k):
//   data chunk16 (row, kb): tile*8192 + (kb&3)*2048 + (row&127)*16
//   scale u32   (row):      tile*512B + (row&31)*16B + ((row>>5)&3)*4B
// ---------------------------------------------------------------------------
#define QOFS_OUT 32768
#define QOFS_SC  36864

__global__ __launch_bounds__(256) void rotquant4_kernel(
    const float* __restrict__ T, u8* __restrict__ Q4, u8* __restrict__ S,
    int K, int ntk, int nkb /* K/1024 */)
{
    __shared__ __align__(16) u8 smem[37120];

    const int tid  = threadIdx.x;
    const int bid  = blockIdx.x;
    const int rblk = bid / nkb;
    const int kblk = bid - rblk * nkb;
    const int row0 = rblk * 8;
    const int kb0  = kblk * 32;
    const int t0g  = (row0 >> 7) * ntk + (kb0 >> 2);
    const int rl   = row0 & 127;

    {
        const float4* src = (const float4*)T;
#pragma unroll
        for (int j = 0; j < 8; ++j) {
            float4 t = src[(size_t)(row0 + j) * (K >> 2) + (kblk << 8) + tid];
            int kb = tid >> 3, i = tid & 7;
            *(float4*)(smem + j * 4096 + kb * 128 + ((i ^ (kb & 7)) << 4)) = t;
        }
    }
    __syncthreads();

    {
        const int rr = tid >> 5;
        const int kb = tid & 31;

        float v[32];
#pragma unroll
        for (int i = 0; i < 8; ++i) {
            float4 t = *(const float4*)(smem + rr * 4096 + kb * 128
                                        + ((i ^ (kb & 7)) << 4));
            v[i*4+0] = t.x; v[i*4+1] = t.y; v[i*4+2] = t.z; v[i*4+3] = t.w;
        }

#pragma unroll
        for (int s = 1; s < 32; s <<= 1) {
#pragma unroll
            for (int i = 0; i < 32; ++i) {
                if (!(i & s)) {
                    float a = v[i], b = v[i | s];
                    v[i] = a + b;
                    v[i | s] = a - b;
                }
            }
        }

        float amax = 0.f;
#pragma unroll
        for (int i = 0; i < 32; ++i) {
            v[i] *= INV_SQRT32;
            amax = fmaxf(amax, fabsf(v[i]));
        }

        u32 ab = __float_as_uint(amax);
        int be = (int)(ab >> 23);
        u32 w[4] = {0u, 0u, 0u, 0u};
        u8 sbyte = 0;
        if (be >= 3) {
            sbyte = (u8)(be - 2);               // E8M0 of 2^(be-129)
            float iscale = __uint_as_float((u32)(256 - be) << 23);
#pragma unroll
            for (int i = 0; i < 32; ++i) {
                float a = v[i] * iscale;        // exact
                float m = fminf(fabsf(a), 6.0f);
                int c = (m < 0.25f) ? 0 :
                        (m < 0.75f) ? 1 :
                        (m < 1.25f) ? 2 :
                        (m < 1.75f) ? 3 :
                        (m < 2.5f)  ? 4 :
                        (m < 3.5f)  ? 5 :
                        (m < 5.0f)  ? 6 : 7;
                c |= (int)((__float_as_uint(a) >> 28) & 8u);
                w[i >> 3] |= (u32)c << (4 * (i & 7));
            }
        }

        uint4 p; p.x = w[0]; p.y = w[1]; p.z = w[2]; p.w = w[3];
        *(uint4*)(smem + QOFS_OUT + rr * 512 + (kb >> 2) * 64 + (kb & 3) * 16) = p;
        smem[QOFS_SC + rr * 32 + (kb >> 2) * 4 + (kb & 3)] = sbyte;
    }
    __syncthreads();

    {
        int tileL = tid >> 5, slot = (tid >> 3) & 3, rr = tid & 7;
        uint4 p = *(const uint4*)(smem + QOFS_OUT + rr * 512 + tileL * 64
                                  + slot * 16);
        ((uint4*)Q4)[(size_t)(t0g + tileL) * 512 + slot * 128 + rl + rr] = p;
    }
    if (tid < 64) {
        int tileL = tid >> 3, rr = tid & 7;
        u32 sc = *(const u32*)(smem + QOFS_SC + rr * 32 + tileL * 4);
        int r7 = rl + rr;   // row within 128-row tile
        ((u32*)S)[(size_t)(t0g + tileL) * 128 + ((r7 & 31) << 2)
                  + ((r7 >> 5) & 3)] = sc;
    }
}

// ---------------------------------------------------------------------------
// Stage 2: EXACT round-10 GEMM (best measured: 330 us, MfmaUtil 39%) with
// ONE change: nontemporal C stores (C is never re-read; normal stores were
// thrashing L3 and evicting the L3-resident fp4 operand panels -- FETCH_SIZE
// showed 214 MB vs 53 MB unique operand bytes).
// ---------------------------------------------------------------------------
__device__ __forceinline__ void gload16(const void* g, void* l)
{
    __builtin_amdgcn_global_load_lds(
        (__attribute__((address_space(1))) void*)g,
        (__attribute__((address_space(3))) void*)l, 16, 0, 0);
}
__device__ __forceinline__ void gload4(const void* g, void* l)
{
    __builtin_amdgcn_global_load_lds(
        (__attribute__((address_space(1))) void*)g,
        (__attribute__((address_space(3))) void*)l, 4, 0, 0);
}

#define BUF_BYTES 34816
#define OFS_B     16384
#define OFS_AS    32768
#define OFS_BS    33792
#define BB0 0
#define BB1 BUF_BYTES
#define BB2 (2 * BUF_BYTES)

__global__ __launch_bounds__(512, 2) void gemm4_bias(
    const u8* __restrict__ A4, const u8* __restrict__ AS,
    const u8* __restrict__ B4, const u8* __restrict__ BS,
    const float* __restrict__ bias, float* __restrict__ C,
    int M, int N, int K)
{
    __shared__ __align__(16) u8 smem[3 * BUF_BYTES];   // 104448 B

    const int tid  = threadIdx.x;
    const int wave = tid >> 6;
    const int lane = tid & 63;
    const int l31  = lane & 31;
    const int lhi  = lane >> 5;
    const int wm   = wave >> 2;   // 2 (M) x 4 (N) wave grid
    const int wn   = wave & 3;
    const int ntk  = K >> 7;
    const int NT   = ntk;

    // XCD-chunked + L2-grouped block ordering
    const int nbn = N >> 8;
    const int nbm = M >> 8;
    int bid = blockIdx.x;
    int bm, bn;
    if (((gridDim.x & 7) == 0) && ((nbm & 7) == 0)) {
        int bpc = nbm >> 3;
        int lb  = __builtin_ctz(bpc);
        int c   = bid & 7;
        int r   = bid >> 3;
        bm = c * bpc + (r & (bpc - 1));
        bn = r >> lb;
    } else {
        bn = bid % nbn;
        bm = bid / nbn;
    }

    v16f acc[4][2];
#pragma unroll
    for (int i = 0; i < 4; ++i)
#pragma unroll
        for (int j = 0; j < 2; ++j)
#pragma unroll
            for (int r = 0; r < 16; ++r) acc[i][j][r] = 0.f;

    // ---- staging constants
    const size_t aRow0 = (size_t)(2 * bm) * ntk;
    const size_t bRow0 = (size_t)(2 * bn) * ntk;
    const int isA = (wave < 4);
    const int w4  = wave & 3;
    const u8* scB = isA ? AS : BS;
    const size_t scT = (size_t)((isA ? 2 * bm : 2 * bn) + (w4 >> 1)) * ntk;
    const int scInner = (w4 & 1) * 256 + lane * 4;
    const int scDst   = (isA ? OFS_AS : OFS_BS) + w4 * 256;
    const int gOfs = wave * 1024 + lane * 16;
    const int lOfs = wave * 1024;

    // ---- per-lane LDS read bases (byte offsets within ONE buffer)
    const int aRB = wm * 8192 + lhi * 2048 + l31 * 16;   // +mi*512 +ks*4096
    const int bRB = OFS_B + (wn >> 1) * 8192 + lhi * 2048
                    + (wn & 1) * 1024 + l31 * 16;        // +ni*512 +ks*4096
    const int asB = OFS_AS + wm * 512 + l31 * 16;        // v4i: u32[mi]
    const int bsB = OFS_BS + (wn >> 1) * 512 + (wn & 1) * 8 + l31 * 16; // v2i
    const int sh0 = lhi * 8;         // ks0 scale byte shift
    const int sh1 = sh0 + 16;        // ks1 scale byte shift

#define STG_A(bofs, kt, r)                                                    \
    gload16(A4 + ((aRow0 + (size_t)(r) * ntk + (kt)) << 13) + gOfs,           \
            smem + (bofs) + (r) * 8192 + lOfs)
#define STG_B(bofs, kt, r)                                                    \
    gload16(B4 + ((bRow0 + (size_t)(r) * ntk + (kt)) << 13) + gOfs,           \
            smem + (bofs) + OFS_B + (r) * 8192 + lOfs)
#define STG_S(bofs, kt)                                                       \
    gload4(scB + ((scT + (kt)) << 9) + scInner, smem + (bofs) + scDst)
#define STAGE(bofs, kt)                                                       \
    do { STG_A(bofs, kt, 0); STG_A(bofs, kt, 1);                              \
         STG_B(bofs, kt, 0); STG_B(bofs, kt, 1); STG_S(bofs, kt); } while (0)

#define MK8(x) __builtin_shufflevector(x, x, 0, 1, 2, 3, -1, -1, -1, -1)
#define MFMA1(mi, ni, AF, BF, SA, SB)                                         \
    acc[mi][ni] = __builtin_amdgcn_mfma_scale_f32_32x32x64_f8f6f4(            \
        MK8(AF), MK8(BF), acc[mi][ni], 4, 4, 0, (int)(SA), 0, (int)(SB))

// Pre-set (carried across tiles): SAv,SBv (scales), B0a,B0b,A0a,A0b (ks0 frags)
#define TILE(CO, NO, PO, kt, ST, REFILL, FINAL)                               \
    do {                                                                      \
        if (ST) STAGE(PO, (kt) + 2);                                          \
        u32 ya0 = ((u32)SAv[0] >> sh0) & 0xffu;                               \
        u32 ya1 = ((u32)SAv[1] >> sh0) & 0xffu;                               \
        u32 ya2 = ((u32)SAv[2] >> sh0) & 0xffu;                               \
        u32 ya3 = ((u32)SAv[3] >> sh0) & 0xffu;                               \
        u32 yb0 = ((u32)SBv[0] >> sh0) & 0xffu;                               \
        u32 yb1 = ((u32)SBv[1] >> sh0) & 0xffu;                               \
        u32 xa0 = ((u32)SAv[0] >> sh1) & 0xffu;                               \
        u32 xa1 = ((u32)SAv[1] >> sh1) & 0xffu;                               \
        u32 xa2 = ((u32)SAv[2] >> sh1) & 0xffu;                               \
        u32 xa3 = ((u32)SAv[3] >> sh1) & 0xffu;                               \
        u32 xb0 = ((u32)SBv[0] >> sh1) & 0xffu;                               \
        u32 xb1 = ((u32)SBv[1] >> sh1) & 0xffu;                               \
        __builtin_amdgcn_s_setprio(1);                                        \
        v4i a2 = *(const v4i*)(smem + (CO) + aRB + 1024);                     \
        v4i a3 = *(const v4i*)(smem + (CO) + aRB + 1536);                     \
        MFMA1(0, 0, A0a, B0a, ya0, yb0); MFMA1(0, 1, A0a, B0b, ya0, yb1);     \
        v4i b1a = *(const v4i*)(smem + (CO) + bRB + 4096);                    \
        v4i b1b = *(const v4i*)(smem + (CO) + bRB + 4608);                    \
        MFMA1(1, 0, A0b, B0a, ya1, yb0); MFMA1(1, 1, A0b, B0b, ya1, yb1);     \
        v4i a10 = *(const v4i*)(smem + (CO) + aRB + 4096);                    \
        v4i a11 = *(const v4i*)(smem + (CO) + aRB + 4608);                    \
        MFMA1(2, 0, a2, B0a, ya2, yb0); MFMA1(2, 1, a2, B0b, ya2, yb1);       \
        v4i a12 = *(const v4i*)(smem + (CO) + aRB + 5120);                    \
        v4i a13 = *(const v4i*)(smem + (CO) + aRB + 5632);                    \
        MFMA1(3, 0, a3, B0a, ya3, yb0); MFMA1(3, 1, a3, B0b, ya3, yb1);       \
        __builtin_amdgcn_s_setprio(0);                                        \
        if (!(FINAL)) {                                                       \
            if (ST) { asm volatile("s_waitcnt vmcnt(5)" ::: "memory"); }      \
            else    { asm volatile("s_waitcnt vmcnt(0)" ::: "memory"); }      \
            __builtin_amdgcn_s_barrier();                                     \
        }                                                                     \
        __builtin_amdgcn_s_setprio(1);                                        \
        if (REFILL) { SAv = *(const v4i*)(smem + (NO) + asB);                 \
                      SBv = *(const v2i*)(smem + (NO) + bsB); }               \
        MFMA1(0, 0, a10, b1a, xa0, xb0); MFMA1(0, 1, a10, b1b, xa0, xb1);     \
        if (REFILL) { B0a = *(const v4i*)(smem + (NO) + bRB);                 \
                      B0b = *(const v4i*)(smem + (NO) + bRB + 512); }         \
        MFMA1(1, 0, a11, b1a, xa1, xb0); MFMA1(1, 1, a11, b1b, xa1, xb1);     \
        if (REFILL) { A0a = *(const v4i*)(smem + (NO) + aRB);                 \
                      A0b = *(const v4i*)(smem + (NO) + aRB + 512); }         \
        MFMA1(2, 0, a12, b1a, xa2, xb0); MFMA1(2, 1, a12, b1b, xa2, xb1);     \
        MFMA1(3, 0, a13, b1a, xa3, xb0); MFMA1(3, 1, a13, b1b, xa3, xb1);     \
        __builtin_amdgcn_s_setprio(0);                                        \
    } while (0)

    // ---- prologue: stage tiles 0,1; land tile 0; pre-read tile 0's first half
    STAGE(BB0, 0);
    STAGE(BB1, 1);
    asm volatile("s_waitcnt vmcnt(5)" ::: "memory");
    __builtin_amdgcn_s_barrier();

    v4i SAv = *(const v4i*)(smem + BB0 + asB);
    v2i SBv = *(const v2i*)(smem + BB0 + bsB);
    v4i B0a = *(const v4i*)(smem + BB0 + bRB);
    v4i B0b = *(const v4i*)(smem + BB0 + bRB + 512);
    v4i A0a = *(const v4i*)(smem + BB0 + aRB);
    v4i A0b = *(const v4i*)(smem + BB0 + aRB + 512);

    // main: tiles 0..NT-3 in rounds of 3 ((NT-2)%3==0 for K=4096)
#pragma unroll 1
    for (int t = 0; t + 2 < NT; t += 3) {
        TILE(BB0, BB1, BB2, t + 0, true, true, false);
        TILE(BB1, BB2, BB0, t + 1, true, true, false);
        TILE(BB2, BB0, BB1, t + 2, true, true, false);
    }
    // epilogue: tile NT-2 (buf0, drain; refill from buf1), tile NT-1 (final)
    TILE(BB0, BB1, BB2, NT - 2, false, true, false);
    TILE(BB1, BB2, BB0, NT - 1, false, false, true);

    // Epilogue: 32x32 C/D: col = lane&31, row = (reg&3)+8*(reg>>2)+4*(lane>>5)
    // NONTEMPORAL stores: C is write-once, never re-read -> don't pollute L2/L3
    const int cb = bn * 256 + wn * 64;
    const int rb = bm * 256 + wm * 128;
#pragma unroll
    for (int ni = 0; ni < 2; ++ni) {
        float bb = bias[cb + ni * 32 + l31];
#pragma unroll
        for (int mi = 0; mi < 4; ++mi) {
#pragma unroll
            for (int reg = 0; reg < 16; ++reg) {
                int row = (reg & 3) + 8 * (reg >> 2) + 4 * lhi;
                __builtin_nontemporal_store(
                    acc[mi][ni][reg] + bb,
                    &C[(size_t)(rb + mi * 32 + row) * N + cb + ni * 32 + l31]);
            }
        }
    }
#undef STG_A
#undef STG_B
#undef STG_S
#undef STAGE
#undef MK8
#undef MFMA1
#undef TILE
}

// ---------------------------------------------------------------------------
extern "C" void kernel_launch(void* const* d_in, const int* in_sizes, int n_in,
                              void* d_out, int out_size, void* d_ws, size_t ws_size,
                              hipStream_t stream)
{
    const float* x    = (const float*)d_in[0];   // [M, K] = [8192, 4096]
    const float* w    = (const float*)d_in[1];   // [O, K] = [16384, 4096]
    const float* bias = (const float*)d_in[2];   // [O]

    const int O = in_sizes[2];            // 16384
    const int K = in_sizes[1] / O;        // 4096
    const int M = in_sizes[0] / K;        // 8192

    u8* x4 = (u8*)d_ws;                           // [M, K/2]  tiled
    u8* w4 = x4 + (size_t)M * (K / 2);            // [O, K/2]  tiled
    u8* xs = w4 + (size_t)O * (K / 2);            // [M, K/32] tiled
    u8* ws = xs + (size_t)M * (K / 32);           // [O, K/32] tiled

    const int ntk = K / 128;
    const int nkb = K / 1024;
    rotquant4_kernel<<<(M / 8) * nkb, 256, 0, stream>>>(x, x4, xs, K, ntk, nkb);
    rotquant4_kernel<<<(O / 8) * nkb, 256, 0, stream>>>(w, w4, ws, K, ntk, nkb);

    dim3 grid((M / 256) * (O / 256));     // 2048 blocks
    gemm4_bias<<<grid, 512, 0, stream>>>(x4, xs, w4, ws, bias, (float*)d_out,
                                         M, O, K);
}